// Round 1
// baseline (5337.026 us; speedup 1.0000x reference)
//
#include <hip/hip_runtime.h>
#include <hip/hip_bf16.h>
#include <stdint.h>

#define D_MODEL 1024
#define VOCAB 50257
#define VP 51200          // padded vocab = VS * ITERS * VT
#define ROWS 4096
#define ROWBLK 32
#define VS 2
#define VH (VP / VS)      // 25600
#define VT 512
#define ITERS (VH / VT)   // 50
#define LN_EPS 1e-5f

typedef short s16x8 __attribute__((ext_vector_type(8)));
typedef short s16x4 __attribute__((ext_vector_type(4)));
typedef float f32x4 __attribute__((ext_vector_type(4)));

__device__ __forceinline__ unsigned short f2bf(float f) {
  union { __hip_bfloat16 h; unsigned short u; } cv;
  cv.h = __float2bfloat16(f);
  return cv.u;
}

// ---------------- prep: W fp32 -> bf16 (rows >= VOCAB zeroed) ----------------
__global__ __launch_bounds__(256) void k_prep_w(const float* __restrict__ w,
                                                unsigned short* __restrict__ wb) {
  const int64_t i0 = ((int64_t)blockIdx.x * 256 + threadIdx.x) * 8;
  const int64_t nval = (int64_t)VOCAB * D_MODEL;  // multiple of 8
  s16x8 o;
  if (i0 < nval) {
    const f32x4* p = reinterpret_cast<const f32x4*>(w + i0);
    f32x4 a = p[0], b = p[1];
    o[0]=f2bf(a[0]); o[1]=f2bf(a[1]); o[2]=f2bf(a[2]); o[3]=f2bf(a[3]);
    o[4]=f2bf(b[0]); o[5]=f2bf(b[1]); o[6]=f2bf(b[2]); o[7]=f2bf(b[3]);
  } else {
    #pragma unroll
    for (int i = 0; i < 8; ++i) o[i] = 0;
  }
  *reinterpret_cast<s16x8*>(wb + i0) = o;
}

// ---------------- prep: emb [V][D] fp32 -> embT bf16 [D][VP] ----------------
__global__ __launch_bounds__(256) void k_prep_embT(const float* __restrict__ emb,
                                                   unsigned short* __restrict__ et) {
  __shared__ float tile[32][33];
  const int v0 = blockIdx.x * 32;
  const int d0 = blockIdx.y * 32;
  const int tx = threadIdx.x, ty = threadIdx.y;  // 32 x 8
  #pragma unroll
  for (int i = 0; i < 4; ++i) {
    const int v = v0 + ty + 8 * i;
    tile[ty + 8 * i][tx] = (v < VOCAB) ? emb[(int64_t)v * D_MODEL + d0 + tx] : 0.f;
  }
  __syncthreads();
  #pragma unroll
  for (int i = 0; i < 4; ++i) {
    const int d = d0 + ty + 8 * i;
    et[(int64_t)d * VP + v0 + tx] = f2bf(tile[tx][ty + 8 * i]);
  }
}

// ---------------- main fused kernel ----------------
// grid 256: bx&1 = vocab split, bx>>1 = row block (32 rows). 8 waves.
// Phase 1: S^T[v][q] = W.Q^T (A=W from global bf16, B=Q from frag-ordered LDS)
// Phase 2: O^T[d][q] += embT.P^T (A=embT from global bf16, B=P from swizzled LDS)
__global__ __launch_bounds__(512, 2)
void k_main(const float* __restrict__ enc, const float* __restrict__ bias,
            const unsigned short* __restrict__ wb, const unsigned short* __restrict__ et,
            float* __restrict__ o_part, float* __restrict__ den_part) {
  __shared__ unsigned short Qf[2 * 32 * 64 * 8];  // 64 KB frag-ordered Q
  __shared__ unsigned short Pl[32 * 512];         // 32 KB P[q][v], XOR-swizzled
  __shared__ float red[32 * 4];

  const int bx = blockIdx.x;
  const int vs = bx & 1;
  const int rb = bx >> 1;
  const int row0 = rb * ROWBLK;
  const int tid = threadIdx.x;
  const int w  = tid >> 6;
  const int l  = tid & 63;
  const int lq = l & 15;
  const int g  = l >> 4;

  // stage Q: chunk c -> q = c&31, k = (c>>5)*8 ; dest frag-ordered so that
  // phase-1 reads frag (qt,ks) at lane l linearly (conflict-free).
  for (int c = tid; c < ROWBLK * (D_MODEL / 8); c += 512) {
    const int q  = c & 31;
    const int kc = c >> 5;
    const f32x4* src = reinterpret_cast<const f32x4*>(enc + (row0 + q) * D_MODEL + kc * 8);
    f32x4 a = src[0], b = src[1];
    s16x8 o;
    o[0]=f2bf(a[0]); o[1]=f2bf(a[1]); o[2]=f2bf(a[2]); o[3]=f2bf(a[3]);
    o[4]=f2bf(b[0]); o[5]=f2bf(b[1]); o[6]=f2bf(b[2]); o[7]=f2bf(b[3]);
    const int qt = q >> 4, ks = kc >> 2, lane = ((kc & 3) << 4) | (q & 15);
    reinterpret_cast<s16x8*>(Qf)[(qt * 32 + ks) * 64 + lane] = o;
  }
  __syncthreads();

  const int qt1 = w & 1;   // phase-1 q-tile of this wave
  const int vtg = w >> 1;  // phase-1 vt-group: vt in [vtg*8, vtg*8+8)
  const f32x4 fzero = {0.f, 0.f, 0.f, 0.f};

  float den = 0.f;
  f32x4 Oacc[8][2];
  #pragma unroll
  for (int i = 0; i < 8; ++i) {
    Oacc[i][0] = fzero; Oacc[i][1] = fzero;
  }

  const int wrow_off = (vtg * 128 + lq) * D_MODEL;
  const int q1 = qt1 * 16 + lq;
  char* Plb = reinterpret_cast<char*>(Pl);

  for (int it = 0; it < ITERS; ++it) {
    const int v0 = vs * VH + it * VT;

    // ---- phase 1 ----
    f32x4 S[8];
    #pragma unroll
    for (int t = 0; t < 8; ++t) S[t] = fzero;
    const unsigned short* wB = wb + v0 * D_MODEL + wrow_off;
    #pragma unroll 1
    for (int ks = 0; ks < 32; ++ks) {
      s16x8 qf = reinterpret_cast<const s16x8*>(Qf)[(qt1 * 32 + ks) * 64 + l];
      const unsigned short* wk = wB + ks * 32 + g * 8;
      #pragma unroll
      for (int t = 0; t < 8; ++t) {
        s16x8 af = *reinterpret_cast<const s16x8*>(wk + t * (16 * D_MODEL));
        S[t] = __builtin_amdgcn_mfma_f32_16x16x32_bf16(af, qf, S[t], 0, 0, 0);
      }
    }
    __syncthreads();  // barrier A: prev phase-2 done reading Pl

    // ---- exp + bias + P write + denom ----
    #pragma unroll
    for (int t = 0; t < 8; ++t) {
      const int vloc = (vtg * 8 + t) * 16 + g * 4;
      const int vg = v0 + vloc;
      float e[4];
      #pragma unroll
      for (int r = 0; r < 4; ++r) {
        const int vv = vg + r;
        const float bv = (vv < VOCAB) ? bias[vv] : 0.f;
        e[r] = (vv < VOCAB) ? __expf(S[t][r] + bv) : 0.f;
        den += e[r];
      }
      s16x4 pk;
      pk[0] = f2bf(e[0]); pk[1] = f2bf(e[1]); pk[2] = f2bf(e[2]); pk[3] = f2bf(e[3]);
      uint32_t byte = (uint32_t)q1 * 1024u + (uint32_t)vloc * 2u;
      byte ^= (uint32_t)(q1 & 7) << 4;
      *reinterpret_cast<s16x4*>(Plb + byte) = pk;
    }
    __syncthreads();  // barrier B: Pl ready

    // ---- phase 2 ----
    const unsigned short* eB = et + (w * 128 + lq) * VP + v0;
    #pragma unroll 1
    for (int ks = 0; ks < 16; ++ks) {
      uint32_t b0 = (uint32_t)lq * 1024u + (uint32_t)(ks * 64 + g * 16);
      b0 ^= (uint32_t)(lq & 7) << 4;
      s16x8 pf0 = *reinterpret_cast<const s16x8*>(Plb + b0);
      uint32_t b1 = (uint32_t)(16 + lq) * 1024u + (uint32_t)(ks * 64 + g * 16);
      b1 ^= (uint32_t)(lq & 7) << 4;  // (16+lq)&7 == lq&7
      s16x8 pf1 = *reinterpret_cast<const s16x8*>(Plb + b1);
      const unsigned short* ek = eB + ks * 32 + g * 8;
      #pragma unroll
      for (int dt = 0; dt < 8; ++dt) {
        s16x8 af = *reinterpret_cast<const s16x8*>(ek + dt * (16 * VP));
        Oacc[dt][0] = __builtin_amdgcn_mfma_f32_16x16x32_bf16(af, pf0, Oacc[dt][0], 0, 0, 0);
        Oacc[dt][1] = __builtin_amdgcn_mfma_f32_16x16x32_bf16(af, pf1, Oacc[dt][1], 0, 0, 0);
      }
    }
    // no barrier here: next phase-1 doesn't touch Pl; barrier A protects Pl rewrite
  }

  // ---- write O partials ----
  float* ob = o_part + (vs * ROWS + row0) * D_MODEL;
  #pragma unroll
  for (int dt = 0; dt < 8; ++dt) {
    const int d = (w * 8 + dt) * 16 + g * 4;
    #pragma unroll
    for (int qt = 0; qt < 2; ++qt) {
      const int q = qt * 16 + lq;
      *reinterpret_cast<f32x4*>(ob + q * D_MODEL + d) = Oacc[dt][qt];
    }
  }

  // ---- denom reduce + write ----
  den += __shfl_xor(den, 16);
  den += __shfl_xor(den, 32);
  if (l < 16) red[q1 * 4 + (w >> 1)] = den;
  __syncthreads();
  if (tid < 32) {
    const float s = red[tid * 4] + red[tid * 4 + 1] + red[tid * 4 + 2] + red[tid * 4 + 3];
    den_part[vs * ROWS + row0 + tid] = s;
  }
}

// ---------------- epilogue: combine partials, residual, LayerNorm ----------------
__global__ __launch_bounds__(256)
void k_ln(const float* __restrict__ enc, const float* __restrict__ o_part,
          const float* __restrict__ den_part, const float* __restrict__ gam,
          const float* __restrict__ bet, float* __restrict__ out) {
  __shared__ float r1[4], r2[4];
  const int row = blockIdx.x;
  const int t = threadIdx.x;
  const int d = t * 4;
  const float den = den_part[row] + den_part[ROWS + row];
  const float inv = 1.f / den;
  const f32x4 a = *reinterpret_cast<const f32x4*>(o_part + row * D_MODEL + d);
  const f32x4 b = *reinterpret_cast<const f32x4*>(o_part + (ROWS + row) * D_MODEL + d);
  const f32x4 e = *reinterpret_cast<const f32x4*>(enc + row * D_MODEL + d);
  f32x4 y;
  #pragma unroll
  for (int j = 0; j < 4; ++j) y[j] = e[j] + (a[j] + b[j]) * inv;
  float s1 = y[0] + y[1] + y[2] + y[3];
  float s2 = y[0]*y[0] + y[1]*y[1] + y[2]*y[2] + y[3]*y[3];
  #pragma unroll
  for (int off = 1; off < 64; off <<= 1) {
    s1 += __shfl_xor(s1, off);
    s2 += __shfl_xor(s2, off);
  }
  if ((t & 63) == 0) { r1[t >> 6] = s1; r2[t >> 6] = s2; }
  __syncthreads();
  const float S1 = r1[0] + r1[1] + r1[2] + r1[3];
  const float S2 = r2[0] + r2[1] + r2[2] + r2[3];
  const float mean = S1 * (1.f / D_MODEL);
  const float var = S2 * (1.f / D_MODEL) - mean * mean;
  const float rs = rsqrtf(var + LN_EPS);
  const f32x4 gv = *reinterpret_cast<const f32x4*>(gam + d);
  const f32x4 bv = *reinterpret_cast<const f32x4*>(bet + d);
  f32x4 o;
  #pragma unroll
  for (int j = 0; j < 4; ++j) o[j] = (y[j] - mean) * rs * gv[j] + bv[j];
  *reinterpret_cast<f32x4*>(out + row * D_MODEL + d) = o;
}

extern "C" void kernel_launch(void* const* d_in, const int* in_sizes, int n_in,
                              void* d_out, int out_size, void* d_ws, size_t ws_size,
                              hipStream_t stream) {
  const float* enc = (const float*)d_in[0];
  const float* pw  = (const float*)d_in[1];
  const float* pb  = (const float*)d_in[2];
  const float* emb = (const float*)d_in[3];
  const float* gam = (const float*)d_in[4];
  const float* bet = (const float*)d_in[5];
  float* out = (float*)d_out;

  size_t off = 0;
  unsigned short* ws_W = (unsigned short*)((char*)d_ws + off); off += (size_t)VP * D_MODEL * 2;
  unsigned short* ws_E = (unsigned short*)((char*)d_ws + off); off += (size_t)D_MODEL * VP * 2;
  float* ws_O = (float*)((char*)d_ws + off); off += (size_t)VS * ROWS * D_MODEL * 4;
  float* ws_D = (float*)((char*)d_ws + off); off += (size_t)VS * ROWS * 4;

  if (off > ws_size) {
    // unambiguous sentinel: ws too small -> absmax ~3.4e38
    hipMemsetAsync(d_out, 0x7f, (size_t)out_size * 4, stream);
    return;
  }

  k_prep_w<<<(VP * D_MODEL / 8) / 256, 256, 0, stream>>>(pw, ws_W);
  dim3 gt(VP / 32, D_MODEL / 32);
  k_prep_embT<<<gt, dim3(32, 8), 0, stream>>>(emb, ws_E);
  k_main<<<256, 512, 0, stream>>>(enc, pb, ws_W, ws_E, ws_O, ws_D);
  k_ln<<<ROWS, 256, 0, stream>>>(enc, ws_O, ws_D, gam, bet, out);
}

// Round 2
// 3313.683 us; speedup vs baseline: 1.6106x; 1.6106x over previous
//
#include <hip/hip_runtime.h>
#include <hip/hip_bf16.h>
#include <stdint.h>

#define D_MODEL 1024
#define VOCAB 50257
#define VP 51200          // padded vocab
#define ROWS 4096
#define ROWBLK 32
#define VS 4
#define VH (VP / VS)      // 12800
#define VT 256
#define ITERS (VH / VT)   // 50
#define LN_EPS 1e-5f

typedef short s16x8 __attribute__((ext_vector_type(8)));
typedef short s16x4 __attribute__((ext_vector_type(4)));
typedef float f32x4 __attribute__((ext_vector_type(4)));

__device__ __forceinline__ unsigned short f2bf(float f) {
  union { __hip_bfloat16 h; unsigned short u; } cv;
  cv.h = __float2bfloat16(f);
  return cv.u;
}

// ---------------- prep: W fp32 -> bf16 (rows >= VOCAB zeroed) ----------------
__global__ __launch_bounds__(256) void k_prep_w(const float* __restrict__ w,
                                                unsigned short* __restrict__ wb) {
  const int64_t i0 = ((int64_t)blockIdx.x * 256 + threadIdx.x) * 8;
  const int64_t nval = (int64_t)VOCAB * D_MODEL;  // multiple of 8
  s16x8 o;
  if (i0 < nval) {
    const f32x4* p = reinterpret_cast<const f32x4*>(w + i0);
    f32x4 a = p[0], b = p[1];
    o[0]=f2bf(a[0]); o[1]=f2bf(a[1]); o[2]=f2bf(a[2]); o[3]=f2bf(a[3]);
    o[4]=f2bf(b[0]); o[5]=f2bf(b[1]); o[6]=f2bf(b[2]); o[7]=f2bf(b[3]);
  } else {
    #pragma unroll
    for (int i = 0; i < 8; ++i) o[i] = 0;
  }
  *reinterpret_cast<s16x8*>(wb + i0) = o;
}

// ---------------- prep: emb [V][D] fp32 -> embT bf16 [D][VP] ----------------
__global__ __launch_bounds__(256) void k_prep_embT(const float* __restrict__ emb,
                                                   unsigned short* __restrict__ et) {
  __shared__ float tile[32][33];
  const int v0 = blockIdx.x * 32;
  const int d0 = blockIdx.y * 32;
  const int tx = threadIdx.x, ty = threadIdx.y;  // 32 x 8
  #pragma unroll
  for (int i = 0; i < 4; ++i) {
    const int v = v0 + ty + 8 * i;
    tile[ty + 8 * i][tx] = (v < VOCAB) ? emb[(int64_t)v * D_MODEL + d0 + tx] : 0.f;
  }
  __syncthreads();
  #pragma unroll
  for (int i = 0; i < 4; ++i) {
    const int d = d0 + ty + 8 * i;
    et[(int64_t)d * VP + v0 + tx] = f2bf(tile[tx][ty + 8 * i]);
  }
}

// ---------------- main fused kernel ----------------
// grid 512. XCD swizzle: xcd = bx&7 (hw round-robin), all blocks on an XCD
// share one vocab split (vs = xcd&3) -> shared W/embT stream in that L2.
// 8 waves; wave w owns v-stripe [w*32, w*32+32) of the VT tile and computes
// BOTH q-tiles (S[2][2]) so each W fragment feeds 2 MFMAs.
__global__ __launch_bounds__(512, 4)
void k_main(const float* __restrict__ enc, const float* __restrict__ bias,
            const unsigned short* __restrict__ wb, const unsigned short* __restrict__ et,
            float* __restrict__ o_part, float* __restrict__ den_part) {
  __shared__ unsigned short Qf[2 * 32 * 64 * 8];  // 64 KB frag-ordered Q
  __shared__ unsigned short Pl[32 * VT];          // 16 KB P[q][v], XOR-swizzled

  const int bx = blockIdx.x;
  const int xcd = bx & 7;
  const int j = bx >> 3;           // [0,64)
  const int vs = xcd & 3;
  const int rb = (xcd >> 2) * 64 + j;   // [0,128)
  const int row0 = rb * ROWBLK;
  const int tid = threadIdx.x;
  const int w  = tid >> 6;
  const int l  = tid & 63;
  const int lq = l & 15;
  const int g  = l >> 4;

  // stage Q: c -> q = c>>7, kc = c&127 (coalesced 32B global reads per lane).
  // dest frag-ordered: frag (qt,ks) lane ((kc&3)<<4)|(q&15).
  for (int c = tid; c < ROWBLK * (D_MODEL / 8); c += 512) {
    const int q  = c >> 7;
    const int kc = c & 127;
    const f32x4* src = reinterpret_cast<const f32x4*>(enc + (size_t)(row0 + q) * D_MODEL + kc * 8);
    f32x4 a = src[0], b = src[1];
    s16x8 o;
    o[0]=f2bf(a[0]); o[1]=f2bf(a[1]); o[2]=f2bf(a[2]); o[3]=f2bf(a[3]);
    o[4]=f2bf(b[0]); o[5]=f2bf(b[1]); o[6]=f2bf(b[2]); o[7]=f2bf(b[3]);
    const int qt = q >> 4, ks = kc >> 2, lane = ((kc & 3) << 4) | (q & 15);
    reinterpret_cast<s16x8*>(Qf)[(qt * 32 + ks) * 64 + lane] = o;
  }
  __syncthreads();

  const f32x4 fzero = {0.f, 0.f, 0.f, 0.f};
  const s16x8* Qv = reinterpret_cast<const s16x8*>(Qf);
  char* Plb = reinterpret_cast<char*>(Pl);

  float denq0 = 0.f, denq1 = 0.f;
  f32x4 Oacc[8][2];
  #pragma unroll
  for (int i = 0; i < 8; ++i) { Oacc[i][0] = fzero; Oacc[i][1] = fzero; }

  for (int it = 0; it < ITERS; ++it) {
    const int v0 = vs * VH + it * VT;

    // ---- phase 1: S^T = W.Q^T, 2-stage register-prefetch pipeline ----
    f32x4 S00 = fzero, S01 = fzero, S10 = fzero, S11 = fzero;
    const unsigned short* wB = wb + (size_t)(v0 + w * 32 + lq) * D_MODEL + g * 8;
    s16x8 a0A = *reinterpret_cast<const s16x8*>(wB);
    s16x8 a1A = *reinterpret_cast<const s16x8*>(wB + 16 * D_MODEL);
    #pragma unroll 1
    for (int ks = 0; ks < 32; ks += 2) {
      s16x8 a0B = *reinterpret_cast<const s16x8*>(wB + (ks + 1) * 32);
      s16x8 a1B = *reinterpret_cast<const s16x8*>(wB + (ks + 1) * 32 + 16 * D_MODEL);
      s16x8 q0 = Qv[ks * 64 + l];
      s16x8 q1 = Qv[(32 + ks) * 64 + l];
      S00 = __builtin_amdgcn_mfma_f32_16x16x32_bf16(a0A, q0, S00, 0, 0, 0);
      S01 = __builtin_amdgcn_mfma_f32_16x16x32_bf16(a0A, q1, S01, 0, 0, 0);
      S10 = __builtin_amdgcn_mfma_f32_16x16x32_bf16(a1A, q0, S10, 0, 0, 0);
      S11 = __builtin_amdgcn_mfma_f32_16x16x32_bf16(a1A, q1, S11, 0, 0, 0);
      a0A = *reinterpret_cast<const s16x8*>(wB + (ks + 2) * 32);
      a1A = *reinterpret_cast<const s16x8*>(wB + (ks + 2) * 32 + 16 * D_MODEL);
      q0 = Qv[(ks + 1) * 64 + l];
      q1 = Qv[(32 + ks + 1) * 64 + l];
      S00 = __builtin_amdgcn_mfma_f32_16x16x32_bf16(a0B, q0, S00, 0, 0, 0);
      S01 = __builtin_amdgcn_mfma_f32_16x16x32_bf16(a0B, q1, S01, 0, 0, 0);
      S10 = __builtin_amdgcn_mfma_f32_16x16x32_bf16(a1B, q0, S10, 0, 0, 0);
      S11 = __builtin_amdgcn_mfma_f32_16x16x32_bf16(a1B, q1, S11, 0, 0, 0);
    }
    __syncthreads();  // barrier A: prev phase-2 done reading Pl

    // ---- exp + bias + P write + denom ----
    // S frag: v = v0 + w*32 + tv*16 + g*4 + r ; q = qt*16 + lq
    #pragma unroll
    for (int tv = 0; tv < 2; ++tv) {
      const f32x4 Sq0 = tv ? S10 : S00;
      const f32x4 Sq1 = tv ? S11 : S01;
      const int vbase = v0 + w * 32 + tv * 16 + g * 4;
      s16x4 p0, p1;
      #pragma unroll
      for (int r = 0; r < 4; ++r) {
        const int vv = vbase + r;
        const bool ok = vv < VOCAB;
        const float bv = ok ? bias[vv] : 0.f;
        const float e0 = ok ? __expf(Sq0[r] + bv) : 0.f;
        const float e1 = ok ? __expf(Sq1[r] + bv) : 0.f;
        denq0 += e0; denq1 += e1;
        p0[r] = f2bf(e0); p1[r] = f2bf(e1);
      }
      const uint32_t vloc2 = (uint32_t)(w * 32 + tv * 16 + g * 4) * 2u;
      uint32_t b0 = (uint32_t)lq * 512u + vloc2;        b0 ^= (uint32_t)(lq & 7) << 4;
      uint32_t b1 = (uint32_t)(16 + lq) * 512u + vloc2; b1 ^= (uint32_t)(lq & 7) << 4;
      *reinterpret_cast<s16x4*>(Plb + b0) = p0;
      *reinterpret_cast<s16x4*>(Plb + b1) = p1;
    }
    __syncthreads();  // barrier B: Pl ready

    // ---- phase 2: O^T += embT.P^T (fully unrolled, compiler pipelines) ----
    const unsigned short* eB = et + (size_t)(w * 128 + lq) * VP + v0 + g * 8;
    #pragma unroll
    for (int ks = 0; ks < 8; ++ks) {
      const uint32_t c = (uint32_t)(ks * 64 + g * 16);
      uint32_t b0 = ((uint32_t)lq * 512u + c) ^ ((uint32_t)(lq & 7) << 4);
      uint32_t b1 = ((uint32_t)(16 + lq) * 512u + c) ^ ((uint32_t)(lq & 7) << 4);
      s16x8 pf0 = *reinterpret_cast<const s16x8*>(Plb + b0);
      s16x8 pf1 = *reinterpret_cast<const s16x8*>(Plb + b1);
      const unsigned short* ek = eB + ks * 32;
      #pragma unroll
      for (int dt = 0; dt < 8; ++dt) {
        s16x8 af = *reinterpret_cast<const s16x8*>(ek + (size_t)dt * 16 * VP);
        Oacc[dt][0] = __builtin_amdgcn_mfma_f32_16x16x32_bf16(af, pf0, Oacc[dt][0], 0, 0, 0);
        Oacc[dt][1] = __builtin_amdgcn_mfma_f32_16x16x32_bf16(af, pf1, Oacc[dt][1], 0, 0, 0);
      }
    }
    // no barrier: next phase-1 doesn't touch Pl; barrier A protects Pl rewrite
  }

  // ---- write O partials: d = w*128 + dt*16 + g*4 + r, q = qt*16 + lq ----
  float* ob = o_part + ((size_t)vs * ROWS + row0) * D_MODEL;
  #pragma unroll
  for (int dt = 0; dt < 8; ++dt) {
    const int d = w * 128 + dt * 16 + g * 4;
    *reinterpret_cast<f32x4*>(ob + (size_t)lq * D_MODEL + d) = Oacc[dt][0];
    *reinterpret_cast<f32x4*>(ob + (size_t)(16 + lq) * D_MODEL + d) = Oacc[dt][1];
  }

  // ---- denom reduce (reuse Pl after sync) ----
  __syncthreads();  // all phase-2 reads of Pl done
  denq0 += __shfl_xor(denq0, 16); denq0 += __shfl_xor(denq0, 32);
  denq1 += __shfl_xor(denq1, 16); denq1 += __shfl_xor(denq1, 32);
  float* red = reinterpret_cast<float*>(Pl);
  if (l < 16) {
    red[w * 32 + lq] = denq0;
    red[w * 32 + 16 + lq] = denq1;
  }
  __syncthreads();
  if (tid < 32) {
    float s = 0.f;
    #pragma unroll
    for (int ww = 0; ww < 8; ++ww) s += red[ww * 32 + tid];
    den_part[(size_t)vs * ROWS + row0 + tid] = s;
  }
}

// ---------------- epilogue: combine partials, residual, LayerNorm ----------------
__global__ __launch_bounds__(256)
void k_ln(const float* __restrict__ enc, const float* __restrict__ o_part,
          const float* __restrict__ den_part, const float* __restrict__ gam,
          const float* __restrict__ bet, float* __restrict__ out) {
  __shared__ float r1[4], r2[4];
  const int row = blockIdx.x;
  const int t = threadIdx.x;
  const int d = t * 4;
  float den = 0.f;
  #pragma unroll
  for (int p = 0; p < VS; ++p) den += den_part[(size_t)p * ROWS + row];
  const float inv = 1.f / den;
  f32x4 acc = {0.f, 0.f, 0.f, 0.f};
  #pragma unroll
  for (int p = 0; p < VS; ++p) {
    const f32x4 a = *reinterpret_cast<const f32x4*>(o_part + ((size_t)p * ROWS + row) * D_MODEL + d);
    #pragma unroll
    for (int jj = 0; jj < 4; ++jj) acc[jj] += a[jj];
  }
  const f32x4 e = *reinterpret_cast<const f32x4*>(enc + (size_t)row * D_MODEL + d);
  f32x4 y;
  #pragma unroll
  for (int jj = 0; jj < 4; ++jj) y[jj] = e[jj] + acc[jj] * inv;
  float s1 = y[0] + y[1] + y[2] + y[3];
  float s2 = y[0]*y[0] + y[1]*y[1] + y[2]*y[2] + y[3]*y[3];
  #pragma unroll
  for (int off = 1; off < 64; off <<= 1) {
    s1 += __shfl_xor(s1, off);
    s2 += __shfl_xor(s2, off);
  }
  if ((t & 63) == 0) { r1[t >> 6] = s1; r2[t >> 6] = s2; }
  __syncthreads();
  const float S1 = r1[0] + r1[1] + r1[2] + r1[3];
  const float S2 = r2[0] + r2[1] + r2[2] + r2[3];
  const float mean = S1 * (1.f / D_MODEL);
  const float var = S2 * (1.f / D_MODEL) - mean * mean;
  const float rs = rsqrtf(var + LN_EPS);
  const f32x4 gv = *reinterpret_cast<const f32x4*>(gam + d);
  const f32x4 bv = *reinterpret_cast<const f32x4*>(bet + d);
  f32x4 o;
  #pragma unroll
  for (int jj = 0; jj < 4; ++jj) o[jj] = (y[jj] - mean) * rs * gv[jj] + bv[jj];
  *reinterpret_cast<f32x4*>(out + (size_t)row * D_MODEL + d) = o;
}

extern "C" void kernel_launch(void* const* d_in, const int* in_sizes, int n_in,
                              void* d_out, int out_size, void* d_ws, size_t ws_size,
                              hipStream_t stream) {
  const float* enc = (const float*)d_in[0];
  const float* pw  = (const float*)d_in[1];
  const float* pb  = (const float*)d_in[2];
  const float* emb = (const float*)d_in[3];
  const float* gam = (const float*)d_in[4];
  const float* bet = (const float*)d_in[5];
  float* out = (float*)d_out;

  size_t off = 0;
  unsigned short* ws_W = (unsigned short*)((char*)d_ws + off); off += (size_t)VP * D_MODEL * 2 + 4096;
  unsigned short* ws_E = (unsigned short*)((char*)d_ws + off); off += (size_t)D_MODEL * VP * 2 + 4096;
  float* ws_O = (float*)((char*)d_ws + off); off += (size_t)VS * ROWS * D_MODEL * 4;
  float* ws_D = (float*)((char*)d_ws + off); off += (size_t)VS * ROWS * 4;

  if (off > ws_size) {
    // unambiguous sentinel: ws too small -> absmax ~3.4e38
    hipMemsetAsync(d_out, 0x7f, (size_t)out_size * 4, stream);
    return;
  }

  k_prep_w<<<(VP * D_MODEL / 8) / 256, 256, 0, stream>>>(pw, ws_W);
  dim3 gt(VP / 32, D_MODEL / 32);
  k_prep_embT<<<gt, dim3(32, 8), 0, stream>>>(emb, ws_E);
  k_main<<<512, 512, 0, stream>>>(enc, pb, ws_W, ws_E, ws_O, ws_D);
  k_ln<<<ROWS, 256, 0, stream>>>(enc, ws_O, ws_D, gam, bet, out);
}

// Round 3
// 1596.517 us; speedup vs baseline: 3.3429x; 2.0756x over previous
//
#include <hip/hip_runtime.h>
#include <hip/hip_bf16.h>
#include <stdint.h>

#define D_MODEL 1024
#define VOCAB 50257
#define VP 51200          // padded vocab = NTILES * 256
#define ROWS 4096
#define RB 64             // rows (q) per block
#define VS 4              // vocab splits
#define VH (VP / VS)      // 12800
#define VT 256            // vocab tile per iter
#define ITERS (VH / VT)   // 50
#define NTILES (VS * ITERS) // 200
#define LN_EPS 1e-5f

typedef short s16x4 __attribute__((ext_vector_type(4)));
typedef short s16x8 __attribute__((ext_vector_type(8)));
typedef float f32x4 __attribute__((ext_vector_type(4)));
typedef float f32x16 __attribute__((ext_vector_type(16)));

__device__ __forceinline__ unsigned short f2bf(float f) {
  union { __hip_bfloat16 h; unsigned short u; } cv;
  cv.h = __float2bfloat16(f);
  return cv.u;
}

// ---- pack W [VOCAB][1024] fp32 -> frag-stream bf16 ----
// chunk id = tile*32768 + w*4096 + ks*64 + l ; each chunk = 16B (8 bf16)
// lane l of frag (tile,w,ks): v = tile*256 + w*32 + (l&31), k = ks*16 + (l>>5)*8
__global__ __launch_bounds__(256) void k_pack_w(const float* __restrict__ wsrc,
                                                unsigned short* __restrict__ wp) {
  const int cid = blockIdx.x * 256 + threadIdx.x;   // < 200*32768 = 6,553,600
  const int l = cid & 63;
  const int ks = (cid >> 6) & 63;
  const int w = (cid >> 12) & 7;
  const int tile = cid >> 15;
  const int v = tile * 256 + w * 32 + (l & 31);
  const int k = ks * 16 + (l >> 5) * 8;
  s16x8 o;
  if (v < VOCAB) {
    const f32x4* p = reinterpret_cast<const f32x4*>(wsrc + (size_t)v * D_MODEL + k);
    f32x4 a = p[0], b = p[1];
    o[0]=f2bf(a[0]); o[1]=f2bf(a[1]); o[2]=f2bf(a[2]); o[3]=f2bf(a[3]);
    o[4]=f2bf(b[0]); o[5]=f2bf(b[1]); o[6]=f2bf(b[2]); o[7]=f2bf(b[3]);
  } else {
    #pragma unroll
    for (int i = 0; i < 8; ++i) o[i] = 0;
  }
  reinterpret_cast<s16x8*>(wp)[cid] = o;
}

// ---- pack emb [VOCAB][1024] fp32 -> transposed frag-stream bf16 ----
// chunk id = tile*32768 + w*4096 + ks*256 + dt*64 + l (ks in [0,16), dt in [0,4))
// lane l holds d = (dt*8+w)*32 + (l&31), v(j) = tile*256 + ks*16 + (l>>5)*8 + j
__global__ __launch_bounds__(256) void k_pack_e(const float* __restrict__ emb,
                                                unsigned short* __restrict__ ep) {
  __shared__ unsigned short tileS[256][33];
  const int tile = blockIdx.x;       // [0,200)
  const int dblk = blockIdx.y;       // [0,32)  == dt*8 + w
  const int w = dblk & 7, dt = dblk >> 3;
  const int t = threadIdx.x;
  // load: row vloc = t, cols dblk*32..+32
  {
    const int v = tile * 256 + t;
    if (v < VOCAB) {
      const f32x4* src = reinterpret_cast<const f32x4*>(emb + (size_t)v * D_MODEL + dblk * 32);
      #pragma unroll
      for (int i = 0; i < 8; ++i) {
        f32x4 a = src[i];
        #pragma unroll
        for (int j = 0; j < 4; ++j) tileS[t][i * 4 + j] = f2bf(a[j]);
      }
    } else {
      #pragma unroll
      for (int i = 0; i < 32; ++i) tileS[t][i] = 0;
    }
  }
  __syncthreads();
  // emit 1024 chunks, 4 per thread
  #pragma unroll
  for (int i = 0; i < 4; ++i) {
    const int c = t + i * 256;
    const int l = c & 63;
    const int ks = c >> 6;
    const int dloc = l & 31;
    s16x8 o;
    #pragma unroll
    for (int j = 0; j < 8; ++j) o[j] = tileS[ks * 16 + (l >> 5) * 8 + j][dloc];
    const size_t cid = (size_t)tile * 32768 + (size_t)w * 4096 + ks * 256 + dt * 64 + l;
    reinterpret_cast<s16x8*>(ep)[cid] = o;
  }
}

// ---- pad bias to VP ----
__global__ __launch_bounds__(256) void k_pack_bias(const float* __restrict__ b,
                                                   float* __restrict__ bp) {
  const int v = blockIdx.x * 256 + threadIdx.x;
  bp[v] = (v < VOCAB) ? b[v] : 0.f;
}

// ---- main fused kernel: 256 blocks (1/CU), 8 waves ----
__global__ __launch_bounds__(512, 2)
void k_main(const float* __restrict__ enc, const float* __restrict__ biasp,
            const unsigned short* __restrict__ Wp, const unsigned short* __restrict__ Ep,
            float* __restrict__ o_part, float* __restrict__ den_part) {
  __shared__ unsigned short Qf[65536];   // 128 KB frag-ordered Q
  __shared__ unsigned short Pl[8192];    // 16 KB: one v-half of P, swizzled

  const int bx = blockIdx.x;
  const int xcd = bx & 7;
  const int vs = xcd & 3;
  const int rb = (xcd >> 2) * 32 + (bx >> 3);   // [0,64)
  const int row0 = rb * RB;
  const int tid = threadIdx.x;
  const int w = tid >> 6;
  const int l = tid & 63;
  const int l31 = l & 31;
  const int lh = l >> 5;

  // ---- stage Q frag-ordered: frag (qt,ks) lane ((kc&1)<<5)|(q&31) ----
  for (int c = tid; c < RB * 128; c += 512) {
    const int q = c >> 7;
    const int kc = c & 127;
    const f32x4* src = reinterpret_cast<const f32x4*>(enc + (size_t)(row0 + q) * D_MODEL + kc * 8);
    f32x4 a = src[0], b = src[1];
    s16x8 o;
    o[0]=f2bf(a[0]); o[1]=f2bf(a[1]); o[2]=f2bf(a[2]); o[3]=f2bf(a[3]);
    o[4]=f2bf(b[0]); o[5]=f2bf(b[1]); o[6]=f2bf(b[2]); o[7]=f2bf(b[3]);
    const int qt = q >> 5, ks = kc >> 1, lane = ((kc & 1) << 5) | (q & 31);
    reinterpret_cast<s16x8*>(Qf)[(qt * 64 + ks) * 64 + lane] = o;
  }
  __syncthreads();

  const s16x8* Qv = reinterpret_cast<const s16x8*>(Qf);
  char* PlB = reinterpret_cast<char*>(Pl);
  const uint32_t swz = (uint32_t)(l31 & 7) << 4;

  float den0 = 0.f, den1 = 0.f;
  f32x16 Oacc[4][2];
  #pragma unroll
  for (int dt = 0; dt < 4; ++dt)
    #pragma unroll
    for (int qt = 0; qt < 2; ++qt)
      #pragma unroll
      for (int i = 0; i < 16; ++i) Oacc[dt][qt][i] = 0.f;

  for (int it = 0; it < ITERS; ++it) {
    const int tile = vs * ITERS + it;

    // ---- phase 1: S^T[v][q] = W.Q^T, frags streamed from packed global ----
    f32x16 S0, S1;
    #pragma unroll
    for (int i = 0; i < 16; ++i) { S0[i] = 0.f; S1[i] = 0.f; }
    const s16x8* wpv = reinterpret_cast<const s16x8*>(Wp) + (size_t)tile * 32768 + w * 4096 + l;
    #pragma unroll 4
    for (int ks = 0; ks < 64; ++ks) {
      s16x8 wf = wpv[ks * 64];
      s16x8 q0 = Qv[(0 * 64 + ks) * 64 + l];
      s16x8 q1 = Qv[(1 * 64 + ks) * 64 + l];
      S0 = __builtin_amdgcn_mfma_f32_32x32x16_bf16(wf, q0, S0, 0, 0, 0);
      S1 = __builtin_amdgcn_mfma_f32_32x32x16_bf16(wf, q1, S1, 0, 0, 0);
    }

    const s16x8* epv = reinterpret_cast<const s16x8*>(Ep) + (size_t)tile * 32768 + w * 4096 + l;

    #pragma unroll
    for (int h = 0; h < 2; ++h) {
      __syncthreads();   // prev phase-2 done reading Pl
      // ---- exp + bias + P-half write + denom (waves owning this v-half) ----
      if ((w >> 2) == h) {
        const int vq = tile * 256 + w * 32 + 4 * lh;      // global padded v, quad base
        const int vloc = (w & 3) * 32 + 4 * lh;           // v offset within half
        const float* bp = biasp + vq;
        const f32x4 bq0 = *reinterpret_cast<const f32x4*>(bp);
        const f32x4 bq1 = *reinterpret_cast<const f32x4*>(bp + 8);
        const f32x4 bq2 = *reinterpret_cast<const f32x4*>(bp + 16);
        const f32x4 bq3 = *reinterpret_cast<const f32x4*>(bp + 24);
        #pragma unroll
        for (int qt = 0; qt < 2; ++qt) {
          const f32x16& Sv = qt ? S1 : S0;
          const uint32_t rowb = (uint32_t)(qt * 32 + l31) * 256u;
          float dl = 0.f;
          #pragma unroll
          for (int m = 0; m < 4; ++m) {
            const f32x4 bq = (m == 0) ? bq0 : (m == 1) ? bq1 : (m == 2) ? bq2 : bq3;
            s16x4 pk;
            #pragma unroll
            for (int r = 0; r < 4; ++r) {
              float e = __expf(Sv[m * 4 + r] + bq[r]);
              if (vq + 8 * m + r >= VOCAB) e = 0.f;
              dl += e;
              pk[r] = f2bf(e);
            }
            const uint32_t byte = (rowb + (uint32_t)(vloc + 8 * m) * 2u) ^ swz;
            *reinterpret_cast<s16x4*>(PlB + byte) = pk;
          }
          if (qt) den1 += dl; else den0 += dl;
        }
      }
      __syncthreads();   // P-half ready
      // ---- phase 2: O^T += embT . P^T over this v-half ----
      #pragma unroll 2
      for (int ks2 = 0; ks2 < 8; ++ks2) {
        const uint32_t voff = (uint32_t)(ks2 * 16 + lh * 8) * 2u;
        s16x8 p0 = *reinterpret_cast<const s16x8*>(PlB + (((uint32_t)l31 * 256u + voff) ^ swz));
        s16x8 p1 = *reinterpret_cast<const s16x8*>(PlB + (((uint32_t)(32 + l31) * 256u + voff) ^ swz));
        const s16x8* ek = epv + (h * 8 + ks2) * 256;
        #pragma unroll
        for (int dt = 0; dt < 4; ++dt) {
          s16x8 ef = ek[dt * 64];
          Oacc[dt][0] = __builtin_amdgcn_mfma_f32_32x32x16_bf16(ef, p0, Oacc[dt][0], 0, 0, 0);
          Oacc[dt][1] = __builtin_amdgcn_mfma_f32_32x32x16_bf16(ef, p1, Oacc[dt][1], 0, 0, 0);
        }
      }
    }
  }

  // ---- write O partials: row = row0 + qt*32 + l31, d = (dt*8+w)*32 + 4*lh + 8m + r ----
  float* ob = o_part + ((size_t)vs * ROWS + row0) * D_MODEL;
  #pragma unroll
  for (int qt = 0; qt < 2; ++qt) {
    #pragma unroll
    for (int dt = 0; dt < 4; ++dt) {
      const f32x16& A = Oacc[dt][qt];
      const int row = qt * 32 + l31;
      const int dbase = (dt * 8 + w) * 32 + 4 * lh;
      #pragma unroll
      for (int m = 0; m < 4; ++m) {
        f32x4 v4 = { A[4 * m], A[4 * m + 1], A[4 * m + 2], A[4 * m + 3] };
        *reinterpret_cast<f32x4*>(ob + (size_t)row * D_MODEL + dbase + 8 * m) = v4;
      }
    }
  }

  // ---- denom reduce (reuse Pl) ----
  __syncthreads();
  den0 += __shfl_xor(den0, 32);
  den1 += __shfl_xor(den1, 32);
  float* red = reinterpret_cast<float*>(Pl);
  if (l < 32) {
    red[(w * 2 + 0) * 32 + l31] = den0;
    red[(w * 2 + 1) * 32 + l31] = den1;
  }
  __syncthreads();
  if (tid < 64) {
    const int qt = tid >> 5, ql = tid & 31;
    float s = 0.f;
    #pragma unroll
    for (int ww = 0; ww < 8; ++ww) s += red[(ww * 2 + qt) * 32 + ql];
    den_part[(size_t)vs * ROWS + row0 + tid] = s;
  }
}

// ---- epilogue: combine partials, residual, LayerNorm ----
__global__ __launch_bounds__(256)
void k_ln(const float* __restrict__ enc, const float* __restrict__ o_part,
          const float* __restrict__ den_part, const float* __restrict__ gam,
          const float* __restrict__ bet, float* __restrict__ out) {
  __shared__ float r1[4], r2[4];
  const int row = blockIdx.x;
  const int t = threadIdx.x;
  const int d = t * 4;
  float den = 0.f;
  #pragma unroll
  for (int p = 0; p < VS; ++p) den += den_part[(size_t)p * ROWS + row];
  const float inv = 1.f / den;
  f32x4 acc = {0.f, 0.f, 0.f, 0.f};
  #pragma unroll
  for (int p = 0; p < VS; ++p) {
    const f32x4 a = *reinterpret_cast<const f32x4*>(o_part + ((size_t)p * ROWS + row) * D_MODEL + d);
    #pragma unroll
    for (int jj = 0; jj < 4; ++jj) acc[jj] += a[jj];
  }
  const f32x4 e = *reinterpret_cast<const f32x4*>(enc + (size_t)row * D_MODEL + d);
  f32x4 y;
  #pragma unroll
  for (int jj = 0; jj < 4; ++jj) y[jj] = e[jj] + acc[jj] * inv;
  float s1 = y[0] + y[1] + y[2] + y[3];
  float s2 = y[0]*y[0] + y[1]*y[1] + y[2]*y[2] + y[3]*y[3];
  #pragma unroll
  for (int off = 1; off < 64; off <<= 1) {
    s1 += __shfl_xor(s1, off);
    s2 += __shfl_xor(s2, off);
  }
  if ((t & 63) == 0) { r1[t >> 6] = s1; r2[t >> 6] = s2; }
  __syncthreads();
  const float S1 = r1[0] + r1[1] + r1[2] + r1[3];
  const float S2 = r2[0] + r2[1] + r2[2] + r2[3];
  const float mean = S1 * (1.f / D_MODEL);
  const float var = S2 * (1.f / D_MODEL) - mean * mean;
  const float rs = rsqrtf(var + LN_EPS);
  const f32x4 gv = *reinterpret_cast<const f32x4*>(gam + d);
  const f32x4 bv = *reinterpret_cast<const f32x4*>(bet + d);
  f32x4 o;
  #pragma unroll
  for (int jj = 0; jj < 4; ++jj) o[jj] = (y[jj] - mean) * rs * gv[jj] + bv[jj];
  *reinterpret_cast<f32x4*>(out + (size_t)row * D_MODEL + d) = o;
}

extern "C" void kernel_launch(void* const* d_in, const int* in_sizes, int n_in,
                              void* d_out, int out_size, void* d_ws, size_t ws_size,
                              hipStream_t stream) {
  const float* enc = (const float*)d_in[0];
  const float* pw  = (const float*)d_in[1];
  const float* pb  = (const float*)d_in[2];
  const float* emb = (const float*)d_in[3];
  const float* gam = (const float*)d_in[4];
  const float* bet = (const float*)d_in[5];
  float* out = (float*)d_out;

  size_t off = 0;
  unsigned short* Wp = (unsigned short*)((char*)d_ws + off); off += (size_t)NTILES * 32768 * 16;  // 104.86 MB
  unsigned short* Ep = (unsigned short*)((char*)d_ws + off); off += (size_t)NTILES * 32768 * 16;  // 104.86 MB
  float* biasp = (float*)((char*)d_ws + off); off += (size_t)VP * 4;                              // 0.2 MB
  float* o_part = (float*)((char*)d_ws + off); off += (size_t)VS * ROWS * D_MODEL * 4;            // 67.1 MB
  float* den_part = (float*)((char*)d_ws + off); off += (size_t)VS * ROWS * 4;

  if (off > ws_size) {
    // unambiguous sentinel: ws too small -> absmax ~3.4e38
    hipMemsetAsync(d_out, 0x7f, (size_t)out_size * 4, stream);
    return;
  }

  k_pack_w<<<NTILES * 32768 / 256, 256, 0, stream>>>(pw, Wp);
  k_pack_e<<<dim3(NTILES, 32), 256, 0, stream>>>(emb, Ep);
  k_pack_bias<<<VP / 256, 256, 0, stream>>>(pb, biasp);
  k_main<<<256, 512, 0, stream>>>(enc, biasp, Wp, Ep, o_part, den_part);
  k_ln<<<ROWS, 256, 0, stream>>>(enc, o_part, den_part, gam, bet, out);
}